// Round 7
// baseline (185.769 us; speedup 1.0000x reference)
//
#include <hip/hip_runtime.h>

// GraphCoordinator: out = x, except rows exactly equal to last_updated_param[p]
// (sequential running scan p=0..15) are replaced with learnable_param[p].
// Matches are ~16 of 1,000,000 rows. Single fused kernel, one pass:
//   - each block copies one contiguous 2048-float4 chunk (256 thr x UNROLL=8)
//   - loads are CACHED (L3 retains ~half of x across graph replays: round-1
//     counters showed steady-state FETCH_SIZE ~250 MB of a 512 MB input);
//     stores are NON-TEMPORAL so the write stream doesn't evict x from L3.
//   - signature check: lane holds sig[tid&15] = last[tid&15][0]; the row-start
//     element (lanes 0/32) is broadcast via __shfl; 1 cmp + 1 ballot per m.
//     On a (rare) hit the wave replays the exact sequential p-loop with
//     full-row 32-lane ballot equality — running semantics in registers.
// Gating is a correct superset: a row can only be mutated mid-scan if it first
// matches some p, which requires an original element-0 signature hit.
// Floor: 512 MB read (~half L3-resident) + 512 MB write.

#define F_DIM 128
#define P_DIM 16
#define UNROLL 8
#define CHUNK (256 * UNROLL)   // float4s per block

// Native clang vector type: __builtin_nontemporal_* rejects HIP_vector_type.
typedef float f32x4 __attribute__((ext_vector_type(4)));

__global__ __launch_bounds__(256) void copy_fix_kernel(
    const float* __restrict__ x,
    const float* __restrict__ learn,
    const float* __restrict__ last,
    float* __restrict__ out,
    int total4)                      // n_rows * 32
{
    const int tid  = threadIdx.x;
    const int half = (tid >> 5) & 1;     // which half-wave (row owner)
    const int sl   = tid & 31;           // float4 slot within the row

    // Per-lane signature: last[tid&15][0] (lanes 16-31/48-63 duplicate 0-15).
    const float mysig = last[(tid & 15) * F_DIM];

    const f32x4* __restrict__ src = reinterpret_cast<const f32x4*>(x);
    f32x4*       __restrict__ dst = reinterpret_cast<f32x4*>(out);

    const int base = blockIdx.x * CHUNK;

    if (base + CHUNK <= total4) {
        // Fast path: full chunk, no guards. (Exact for N=1M: 32M/2048=15625.)
        const int i0 = base + tid;

        f32x4 v[UNROLL];
        #pragma unroll
        for (int m = 0; m < UNROLL; ++m)
            v[m] = src[i0 + m * 256];

        #pragma unroll
        for (int m = 0; m < UNROLL; ++m) {
            // Row starts sit in lanes 0 and 32 (base, m*256 are multiples
            // of 32 float4s = one row). Broadcast within each half-wave.
            const float bv = __shfl(v[m].x, tid & 32);
            if (__any(bv == mysig)) {
                // Cold path (~16 waves total across the grid): exact
                // sequential running-semantics replay for this wave's 2 rows.
                for (int p = 0; p < P_DIM; ++p) {
                    const f32x4 lp =
                        *reinterpret_cast<const f32x4*>(&last[p * F_DIM + sl * 4]);
                    const bool eq = (v[m].x == lp.x) & (v[m].y == lp.y) &
                                    (v[m].z == lp.z) & (v[m].w == lp.w);
                    const unsigned long long bm = __ballot(eq);
                    const unsigned int mh = (unsigned int)(bm >> (half * 32));
                    if (mh == 0xFFFFFFFFu)
                        v[m] = *reinterpret_cast<const f32x4*>(
                                   &learn[p * F_DIM + sl * 4]);
                }
            }
        }

        #pragma unroll
        for (int m = 0; m < UNROLL; ++m)
            __builtin_nontemporal_store(v[m], &dst[i0 + m * 256]);
    } else {
        // Guarded tail block (empty for N=1M).
        #pragma unroll
        for (int m = 0; m < UNROLL; ++m) {
            const int i4 = base + tid + m * 256;
            if (i4 >= total4) continue;
            f32x4 v = src[i4];
            const float bv = __shfl(v.x, tid & 32);
            if (__any(bv == mysig)) {
                for (int p = 0; p < P_DIM; ++p) {
                    const f32x4 lp =
                        *reinterpret_cast<const f32x4*>(&last[p * F_DIM + sl * 4]);
                    const bool eq = (v.x == lp.x) & (v.y == lp.y) &
                                    (v.z == lp.z) & (v.w == lp.w);
                    const unsigned long long bm = __ballot(eq);
                    const unsigned int mh = (unsigned int)(bm >> (half * 32));
                    if (mh == 0xFFFFFFFFu)
                        v = *reinterpret_cast<const f32x4*>(
                                &learn[p * F_DIM + sl * 4]);
                }
            }
            __builtin_nontemporal_store(v, &dst[i4]);
        }
    }
}

extern "C" void kernel_launch(void* const* d_in, const int* in_sizes, int n_in,
                              void* d_out, int out_size, void* d_ws, size_t ws_size,
                              hipStream_t stream) {
    // setup_inputs() order: x [N*F] f32, batch [N] i64 (unused),
    //                       learnable_param [P*F] f32, last_updated_param [P*F] f32
    const float* x     = (const float*)d_in[0];
    const float* learn = (const float*)d_in[2];
    const float* last  = (const float*)d_in[3];
    float*       out   = (float*)d_out;

    const int n_rows = in_sizes[0] / F_DIM;    // 1,000,000
    const int total4 = n_rows * (F_DIM / 4);   // 32,000,000 float4s
    const int grid   = (total4 + CHUNK - 1) / CHUNK;  // 15625 for N=1M

    copy_fix_kernel<<<grid, 256, 0, stream>>>(x, learn, last, out, total4);
}